// Round 10
// baseline (20.682 us; speedup 1.0000x reference)
//
#include <hip/hip_runtime.h>
#include <math.h>

// TreeCrfLoss, two-dispatch:
//   pot = sum_i U[i, tl[i]]  +  sum_{c>=1} E[c, tl[(c-1)/4], tl[c]]
//   out = z - pot,  z = logsumexp(beliefs[0, 0:16])
// Partial (unchanged from R9, proven 20.37us): 1024 blocks = 4/CU, thread t
//   handles nodes {2t,2t+1}; BW-bound at ~92% of the random-line gather
//   roofline (MLP maxed: all ~1M gathers in flight; occupancy-insensitive).
// Finalize v3: 1024 threads, ONE partials load each (single latency), while
//   wave 0 lanes 0-15 concurrently compute logsumexp(beliefs[0:16]) via
//   shfl_xor — beliefs latency + lsse chain hidden under partials reduce.
// (Fusion closed: memset-node +75us, coop +145us, tag-spin +40us. Atomic
//  single-pass closed: d_out not re-zeroed between replays.)

#define NTHR 256
#define NBLK 1024   // 4 blocks/CU; partials size fixed at NBLK

__device__ __forceinline__ float nt_load(const float* p) {
    return __builtin_nontemporal_load(p);
}

__global__ __launch_bounds__(NTHR) void tree_crf_partial(
    const float* __restrict__ U,      // [N,16]
    const float* __restrict__ E,      // [N,16,16]
    const int* __restrict__ tl,       // [N]
    float* __restrict__ partials,     // [NBLK]
    int N)
{
    const int tid = blockIdx.x * NTHR + threadIdx.x;
    float acc = 0.0f;

    // grid-stride over node pairs (one iteration for N <= 524288)
    for (int n0 = tid << 1; n0 < N; n0 += (NBLK * NTHR) << 1) {
        const int n1 = n0 + 1;
        if (n1 < N) {
            const int2 l2 = *reinterpret_cast<const int2*>(tl + n0);  // 8B aligned
            const int p1 = tl[n0 >> 2];                               // parent label of n1
            const int p0 = (n0 >= 1) ? tl[(n0 - 1) >> 2] : 0;         // parent label of n0

            const float u0 = nt_load(&U[((size_t)n0 << 4) + l2.x]);
            const float u1 = nt_load(&U[((size_t)n1 << 4) + l2.y]);
            const float e1 = nt_load(&E[((size_t)n1 << 8) + p1 * 16 + l2.y]);
            float e0 = 0.0f;
            if (n0 >= 1)
                e0 = nt_load(&E[((size_t)n0 << 8) + p0 * 16 + l2.x]);
            acc += (u0 + u1) + (e0 + e1);
        } else {                       // single tail node (N odd)
            const int l = tl[n0];
            acc += U[((size_t)n0 << 4) + l];
            if (n0 >= 1)
                acc += E[((size_t)n0 << 8) + tl[(n0 - 1) >> 2] * 16 + l];
        }
    }

    // 64-lane wave reduction + LDS across the 4 waves
    #pragma unroll
    for (int off = 32; off > 0; off >>= 1)
        acc += __shfl_down(acc, off, 64);
    __shared__ float s[NTHR / 64];
    const int lane = threadIdx.x & 63;
    const int wave = threadIdx.x >> 6;
    if (lane == 0) s[wave] = acc;
    __syncthreads();
    if (threadIdx.x == 0) {
        float v = 0.0f;
        #pragma unroll
        for (int w = 0; w < NTHR / 64; ++w) v += s[w];
        partials[blockIdx.x] = v;   // every block writes (all slots valid)
    }
}

__global__ __launch_bounds__(1024) void tree_crf_finalize(
    const float* __restrict__ beliefs,   // [N,16], only row 0 used
    const float* __restrict__ partials,  // [NBLK], all slots valid
    float* __restrict__ out)
{
    const int t = threadIdx.x;
    // issue the single partials load immediately (one latency, all parallel)
    float p = partials[t];

    __shared__ float s[NBLK / 64];   // 16 wave sums
    __shared__ float zsh;

    // wave 0, lanes 0-15: logsumexp(beliefs[0:16]) — overlapped with the
    // partials-load latency of the other 15 waves. shfl_xor offsets 1,2,4,8
    // reduce strictly within 16-lane groups (no contamination from lanes 16+).
    if (t < 64) {
        const float b = (t < 16) ? beliefs[t] : -INFINITY;
        float m = b;
        #pragma unroll
        for (int off = 1; off < 16; off <<= 1)
            m = fmaxf(m, __shfl_xor(m, off, 64));
        float e = (t < 16) ? __expf(b - m) : 0.0f;
        #pragma unroll
        for (int off = 1; off < 16; off <<= 1)
            e += __shfl_xor(e, off, 64);
        if (t == 0) zsh = m + __logf(e);
    }

    // 64-lane wave reduction of the partials
    #pragma unroll
    for (int off = 32; off > 0; off >>= 1)
        p += __shfl_down(p, off, 64);
    if ((t & 63) == 0) s[t >> 6] = p;
    __syncthreads();

    if (t == 0) {
        float pot = 0.0f;
        #pragma unroll
        for (int w = 0; w < NBLK / 64; ++w) pot += s[w];
        out[0] = zsh - pot;   // -(pot - z)
    }
}

extern "C" void kernel_launch(void* const* d_in, const int* in_sizes, int n_in,
                              void* d_out, int out_size, void* d_ws, size_t ws_size,
                              hipStream_t stream) {
    const float* U       = (const float*)d_in[0];   // unary_potentials [N,16]
    const float* E       = (const float*)d_in[1];   // edge_potentials [N,16,16]
    const float* beliefs = (const float*)d_in[2];   // beliefs [N,16]
    const int*   tl      = (const int*)d_in[3];     // true_labels [N]
    const int N = in_sizes[3];

    float* partials = (float*)d_ws;   // NBLK floats, fully overwritten each call
    float* out      = (float*)d_out;

    tree_crf_partial<<<NBLK, NTHR, 0, stream>>>(U, E, tl, partials, N);
    tree_crf_finalize<<<1, 1024, 0, stream>>>(beliefs, partials, out);
}

// Round 11
// 20.403 us; speedup vs baseline: 1.0137x; 1.0137x over previous
//
#include <hip/hip_runtime.h>

// TreeCrfLoss, two-dispatch (FINAL — best measured 20.37us):
//   pot = sum_i U[i, tl[i]]  +  sum_{c>=1} E[c, tl[(c-1)/4], tl[c]]
//   out = z - pot,  z = logsumexp(beliefs[0, 0:16])
// Partial: 1024 blocks = exactly 4/CU, thread t handles nodes {2t,2t+1};
//   BW-bound at ~92% of the 98 MB random-line gather roofline (U 32MB +
//   E 64MB @128B-line granule + tl 2MB ~= 15.6us floor at 6.3 TB/s).
//   Occupancy- and instruction-count-insensitive (R1/R6 A/B).
// Finalize: 256 threads, 4 unrolled independent loads (single memory
//   latency), LDS tree; remaining cost ~= graph-replay launch overhead.
// Closed paths: fusion (memset-node +75us, coop +145us, tag-spin +40us —
//   the dispatch boundary is the cheapest device-wide sync); float-atomic
//   single-pass (d_out not re-zeroed between replays); 64-thread finalize
//   (+3.5us, load-loop latency chain); 1024-thread finalize (neutral).

#define NTHR 256
#define NBLK 1024   // 4 blocks/CU; partials size fixed at NBLK

__device__ __forceinline__ float nt_load(const float* p) {
    return __builtin_nontemporal_load(p);
}

__global__ __launch_bounds__(NTHR) void tree_crf_partial(
    const float* __restrict__ U,      // [N,16]
    const float* __restrict__ E,      // [N,16,16]
    const int* __restrict__ tl,       // [N]
    float* __restrict__ partials,     // [NBLK]
    int N)
{
    const int tid = blockIdx.x * NTHR + threadIdx.x;
    float acc = 0.0f;

    // grid-stride over node pairs (one iteration for N <= 524288)
    for (int n0 = tid << 1; n0 < N; n0 += (NBLK * NTHR) << 1) {
        const int n1 = n0 + 1;
        if (n1 < N) {
            const int2 l2 = *reinterpret_cast<const int2*>(tl + n0);  // 8B aligned
            const int p1 = tl[n0 >> 2];                               // parent label of n1
            const int p0 = (n0 >= 1) ? tl[(n0 - 1) >> 2] : 0;         // parent label of n0

            const float u0 = nt_load(&U[((size_t)n0 << 4) + l2.x]);
            const float u1 = nt_load(&U[((size_t)n1 << 4) + l2.y]);
            const float e1 = nt_load(&E[((size_t)n1 << 8) + p1 * 16 + l2.y]);
            float e0 = 0.0f;
            if (n0 >= 1)
                e0 = nt_load(&E[((size_t)n0 << 8) + p0 * 16 + l2.x]);
            acc += (u0 + u1) + (e0 + e1);
        } else {                       // single tail node (N odd)
            const int l = tl[n0];
            acc += U[((size_t)n0 << 4) + l];
            if (n0 >= 1)
                acc += E[((size_t)n0 << 8) + tl[(n0 - 1) >> 2] * 16 + l];
        }
    }

    // 64-lane wave reduction + LDS across the 4 waves
    #pragma unroll
    for (int off = 32; off > 0; off >>= 1)
        acc += __shfl_down(acc, off, 64);
    __shared__ float s[NTHR / 64];
    const int lane = threadIdx.x & 63;
    const int wave = threadIdx.x >> 6;
    if (lane == 0) s[wave] = acc;
    __syncthreads();
    if (threadIdx.x == 0) {
        float v = 0.0f;
        #pragma unroll
        for (int w = 0; w < NTHR / 64; ++w) v += s[w];
        partials[blockIdx.x] = v;   // every block writes (all slots valid)
    }
}

__global__ __launch_bounds__(NTHR) void tree_crf_finalize(
    const float* __restrict__ beliefs,   // [N,16], only row 0 used
    const float* __restrict__ partials,  // [NBLK], all slots valid
    float* __restrict__ out)
{
    // 4 independent loads per thread — one memory latency, no loop deps
    const int t = threadIdx.x;
    const float a0 = partials[t];
    const float a1 = partials[t + 256];
    const float a2 = partials[t + 512];
    const float a3 = partials[t + 768];
    float acc = (a0 + a1) + (a2 + a3);

    #pragma unroll
    for (int off = 32; off > 0; off >>= 1)
        acc += __shfl_down(acc, off, 64);
    __shared__ float s[NTHR / 64];
    const int lane = t & 63;
    const int wave = t >> 6;
    if (lane == 0) s[wave] = acc;
    __syncthreads();
    if (t == 0) {
        float pot = 0.0f;
        #pragma unroll
        for (int w = 0; w < NTHR / 64; ++w) pot += s[w];
        float m = beliefs[0];
        #pragma unroll
        for (int j = 1; j < 16; ++j) m = fmaxf(m, beliefs[j]);
        float se = 0.0f;
        #pragma unroll
        for (int j = 0; j < 16; ++j) se += __expf(beliefs[j] - m);
        const float z = m + __logf(se);
        out[0] = z - pot;   // -(pot - z)
    }
}

extern "C" void kernel_launch(void* const* d_in, const int* in_sizes, int n_in,
                              void* d_out, int out_size, void* d_ws, size_t ws_size,
                              hipStream_t stream) {
    const float* U       = (const float*)d_in[0];   // unary_potentials [N,16]
    const float* E       = (const float*)d_in[1];   // edge_potentials [N,16,16]
    const float* beliefs = (const float*)d_in[2];   // beliefs [N,16]
    const int*   tl      = (const int*)d_in[3];     // true_labels [N]
    const int N = in_sizes[3];

    float* partials = (float*)d_ws;   // NBLK floats, fully overwritten each call
    float* out      = (float*)d_out;

    tree_crf_partial<<<NBLK, NTHR, 0, stream>>>(U, E, tl, partials, N);
    tree_crf_finalize<<<1, NTHR, 0, stream>>>(beliefs, partials, out);
}